// Round 1
// baseline (50597.482 us; speedup 1.0000x reference)
//
#include <hip/hip_runtime.h>
#include <stdint.h>

// TreeGenerator: persistent cooperative-style kernel, 256 blocks x 256 thr.
// 3 grid barriers per expand step; pop/inactive steps are block-local.
// Whh1/Wih2/Whh2 LDS-resident (144KB/CU); Wih1 + active Wa block streamed.

#define NBLK   256
#define NTHR   256
#define HID_   1024
#define RPB    12      // gate rows per block (3 gates x 4 h-indices)
#define NSTEP  1024
#define STK    1028
#define NUMNT  16
#define JAX_PARTITIONABLE 1   // jax >= 0.4.30 default; flip to 0 if actions mismatch

__device__ __forceinline__ uint32_t rotl32(uint32_t v, int d){ return (v<<d)|(v>>(32-d)); }

__device__ __forceinline__ void tf2x32(uint32_t k0, uint32_t k1, uint32_t x0, uint32_t x1,
                                       uint32_t& o0, uint32_t& o1){
  uint32_t k2 = k0 ^ k1 ^ 0x1BD11BDAu;
  x0 += k0; x1 += k1;
  x0+=x1; x1=rotl32(x1,13); x1^=x0;
  x0+=x1; x1=rotl32(x1,15); x1^=x0;
  x0+=x1; x1=rotl32(x1,26); x1^=x0;
  x0+=x1; x1=rotl32(x1, 6); x1^=x0;
  x0+=k1; x1+=k2+1u;
  x0+=x1; x1=rotl32(x1,17); x1^=x0;
  x0+=x1; x1=rotl32(x1,29); x1^=x0;
  x0+=x1; x1=rotl32(x1,16); x1^=x0;
  x0+=x1; x1=rotl32(x1,24); x1^=x0;
  x0+=k2; x1+=k0+2u;
  x0+=x1; x1=rotl32(x1,13); x1^=x0;
  x0+=x1; x1=rotl32(x1,15); x1^=x0;
  x0+=x1; x1=rotl32(x1,26); x1^=x0;
  x0+=x1; x1=rotl32(x1, 6); x1^=x0;
  x0+=k0; x1+=k1+3u;
  x0+=x1; x1=rotl32(x1,17); x1^=x0;
  x0+=x1; x1=rotl32(x1,29); x1^=x0;
  x0+=x1; x1=rotl32(x1,16); x1^=x0;
  x0+=x1; x1=rotl32(x1,24); x1^=x0;
  x0+=k1; x1+=k2+4u;
  x0+=x1; x1=rotl32(x1,13); x1^=x0;
  x0+=x1; x1=rotl32(x1,15); x1^=x0;
  x0+=x1; x1=rotl32(x1,26); x1^=x0;
  x0+=x1; x1=rotl32(x1, 6); x1^=x0;
  x0+=k2; x1+=k0+5u;
  o0 = x0; o1 = x1;
}

__device__ __forceinline__ float gumbel_at(int t, int q){
  uint32_t fk0, fk1, a, c, bits;
  tf2x32(0u, 42u, 0u, (uint32_t)t, fk0, fk1);   // fold_in(key(42), t)
#if JAX_PARTITIONABLE
  tf2x32(fk0, fk1, 0u, (uint32_t)q, a, c);
  bits = a ^ c;
#else
  if (q < 4096){ tf2x32(fk0, fk1, (uint32_t)q, (uint32_t)(q+4096), a, c); bits = a; }
  else         { tf2x32(fk0, fk1, (uint32_t)(q-4096), (uint32_t)q, a, c); bits = c; }
#endif
  float f = __uint_as_float((bits >> 9) | 0x3f800000u) - 1.0f;
  float u = fmaxf(1.17549435e-38f, f);          // matches max(tiny, f*(1-tiny)+tiny)
  return -logf(-logf(u));
}

__device__ __forceinline__ float sigf(float x){ return 0.5f + 0.5f * tanhf(0.5f * x); }

__device__ __forceinline__ void gbar(unsigned* cnt, unsigned tgt){
  __syncthreads();
  if (threadIdx.x == 0){
    __threadfence();  // release: flush our writes device-wide
    __hip_atomic_fetch_add(cnt, 1u, __ATOMIC_RELAXED, __HIP_MEMORY_SCOPE_AGENT);
    while (__hip_atomic_load(cnt, __ATOMIC_RELAXED, __HIP_MEMORY_SCOPE_AGENT) < tgt)
      __builtin_amdgcn_s_sleep(2);
    __threadfence();  // acquire: invalidate stale cache lines
  }
  __syncthreads();
}

__global__ __launch_bounds__(NTHR, 1)
void tree_gen(const float* __restrict__ emb,  const float* __restrict__ Wih1,
              const float* __restrict__ Whh1, const float* __restrict__ bih1,
              const float* __restrict__ bhh1, const float* __restrict__ Wih2,
              const float* __restrict__ Whh2, const float* __restrict__ bih2,
              const float* __restrict__ bhh2, const float* __restrict__ Wa,
              const float* __restrict__ ba,   const float* __restrict__ h0,
              const int* __restrict__ ctab,
              float* __restrict__ out,
              float* __restrict__ h1g, float* __restrict__ h2g,
              float* __restrict__ pval, int* __restrict__ pidx,
              unsigned* __restrict__ cnt)
{
  __shared__ __align__(16) float sWhh1[RPB*HID_];   // 48 KB
  __shared__ __align__(16) float sWih2[RPB*HID_];   // 48 KB
  __shared__ __align__(16) float sWhh2[RPB*HID_];   // 48 KB
  __shared__ short sSym[STK];
  __shared__ short sAct[STK];
  __shared__ float sGh1[RPB], sGh2[RPB], sGi[RPB];
  __shared__ float sBih1[RPB], sBih2[RPB], sBhh1[RPB], sBhh2[RPB];
  __shared__ float sLV[2];
  __shared__ float sRv[4];
  __shared__ int   sRi[4];
  __shared__ int   sPtr, sPrev;

  const int tid  = threadIdx.x;
  const int b    = blockIdx.x;
  const int wid  = tid >> 6;
  const int lane = tid & 63;
  unsigned ep = 0;

  // ---- stage this block's 12 rows of each recurrent matrix into LDS ----
  for (int j = 0; j < RPB; ++j){
    const int r = (j >> 2) * HID_ + (b << 2) + (j & 3);
    const float* a1 = Whh1 + (size_t)r * HID_;
    const float* a2 = Wih2 + (size_t)r * HID_;
    const float* a3 = Whh2 + (size_t)r * HID_;
    for (int c = tid * 4; c < HID_; c += NTHR * 4){
      *(float4*)&sWhh1[j*HID_ + c] = *(const float4*)(a1 + c);
      *(float4*)&sWih2[j*HID_ + c] = *(const float4*)(a2 + c);
      *(float4*)&sWhh2[j*HID_ + c] = *(const float4*)(a3 + c);
    }
  }
  if (tid < RPB){
    const int r = (tid >> 2) * HID_ + (b << 2) + (tid & 3);
    sBih1[tid] = bih1[r]; sBih2[tid] = bih2[r];
    sBhh1[tid] = bhh1[r]; sBhh2[tid] = bhh2[r];
  }
  if (tid == 0){ sSym[0] = 0; sAct[0] = -1; sPtr = 1; sPrev = -1; }
  if (tid < 4){
    h1g[(b<<2)+tid] = h0[(b<<2)+tid];
    h2g[(b<<2)+tid] = h0[HID_+(b<<2)+tid];
  }
  __syncthreads();

  // ---- initial gh1 = Whh1@h0[0]+bhh1 ; gh2 = Whh2@h0[1]+bhh2 (local rows) ----
  {
    float4 x1[4], x2[4];
    #pragma unroll
    for (int it=0; it<4; ++it){
      x1[it] = *(const float4*)(h0 + 4*lane + 256*it);
      x2[it] = *(const float4*)(h0 + HID_ + 4*lane + 256*it);
    }
    for (int j = wid; j < RPB; j += 4){
      float a1 = 0.f, a2 = 0.f;
      #pragma unroll
      for (int it=0; it<4; ++it){
        float4 w1 = *(const float4*)&sWhh1[j*HID_ + 4*lane + 256*it];
        float4 w2 = *(const float4*)&sWhh2[j*HID_ + 4*lane + 256*it];
        a1 += w1.x*x1[it].x + w1.y*x1[it].y + w1.z*x1[it].z + w1.w*x1[it].w;
        a2 += w2.x*x2[it].x + w2.y*x2[it].y + w2.z*x2[it].z + w2.w*x2[it].w;
      }
      #pragma unroll
      for (int m=32; m; m>>=1){ a1 += __shfl_xor(a1, m); a2 += __shfl_xor(a2, m); }
      if (lane == 0){ sGh1[j] = a1 + sBhh1[j]; sGh2[j] = a2 + sBhh2[j]; }
    }
  }
  __syncthreads();

  for (int t = 0; t < NSTEP; ++t){
    const int  ptr    = sPtr;
    const bool active = ptr > 0;
    const int  idx    = active ? (ptr - 1) : 0;
    const int  sym    = sSym[idx];
    const int  parent = sAct[idx];
    const int  prev   = sPrev;
    const bool expand = active && (sym < NUMNT);

    if (!expand){
      // pop / inactive: carries (h, prev, gh-pre) unchanged; no cross-block work
      __syncthreads();
      if (tid == 0){
        if (active) sPtr = ptr - 1;
        if (b == 0) out[t] = -1.0f;
      }
      __syncthreads();
      continue;
    }

    // ---------- phase A: gi1 = Wih1 @ [emb[prev+1]; emb[parent+1]] ; h1 ----------
    {
      const float* embP = emb + (size_t)(prev + 1) * HID_;
      const float* embQ = emb + (size_t)(parent + 1) * HID_;
      float4 xp[4], xq[4];
      #pragma unroll
      for (int it=0; it<4; ++it){
        xp[it] = *(const float4*)(embP + 4*lane + 256*it);
        xq[it] = *(const float4*)(embQ + 4*lane + 256*it);
      }
      for (int j = wid; j < RPB; j += 4){
        const int r = (j >> 2) * HID_ + (b << 2) + (j & 3);
        const float* wr = Wih1 + (size_t)r * 2048;
        float acc = 0.f;
        #pragma unroll
        for (int it=0; it<4; ++it){
          float4 w = *(const float4*)(wr + 4*lane + 256*it);
          acc += w.x*xp[it].x + w.y*xp[it].y + w.z*xp[it].z + w.w*xp[it].w;
        }
        #pragma unroll
        for (int it=0; it<4; ++it){
          float4 w = *(const float4*)(wr + 1024 + 4*lane + 256*it);
          acc += w.x*xq[it].x + w.y*xq[it].y + w.z*xq[it].z + w.w*xq[it].w;
        }
        #pragma unroll
        for (int m=32; m; m>>=1) acc += __shfl_xor(acc, m);
        if (lane == 0) sGi[j] = acc + sBih1[j];
      }
      __syncthreads();
      if (tid < 4){
        const int i = (b<<2) + tid;
        float rr = sigf(sGi[tid]    + sGh1[tid]);
        float zz = sigf(sGi[4+tid]  + sGh1[4+tid]);
        float nn = tanhf(sGi[8+tid] + rr * sGh1[8+tid]);
        h1g[i] = (1.f - zz)*nn + zz*h1g[i];
      }
    }
    gbar(cnt, (unsigned)NBLK * (++ep));   // h1 complete

    // ---------- phase B: gi2 = Wih2@h1 -> h2 ; gh1_next = Whh1@h1 ----------
    {
      float4 xr[4];
      #pragma unroll
      for (int it=0; it<4; ++it) xr[it] = *(const float4*)(h1g + 4*lane + 256*it);
      for (int j = wid; j < RPB; j += 4){
        float ai = 0.f, ah = 0.f;
        #pragma unroll
        for (int it=0; it<4; ++it){
          float4 w2 = *(const float4*)&sWih2[j*HID_ + 4*lane + 256*it];
          float4 w1 = *(const float4*)&sWhh1[j*HID_ + 4*lane + 256*it];
          ai += w2.x*xr[it].x + w2.y*xr[it].y + w2.z*xr[it].z + w2.w*xr[it].w;
          ah += w1.x*xr[it].x + w1.y*xr[it].y + w1.z*xr[it].z + w1.w*xr[it].w;
        }
        #pragma unroll
        for (int m=32; m; m>>=1){ ai += __shfl_xor(ai, m); ah += __shfl_xor(ah, m); }
        if (lane == 0){ sGi[j] = ai + sBih2[j]; sGh1[j] = ah + sBhh1[j]; }
      }
      __syncthreads();
      if (tid < 4){
        const int i = (b<<2) + tid;
        float rr = sigf(sGi[tid]    + sGh2[tid]);
        float zz = sigf(sGi[4+tid]  + sGh2[4+tid]);
        float nn = tanhf(sGi[8+tid] + rr * sGh2[8+tid]);
        h2g[i] = (1.f - zz)*nn + zz*h2g[i];
      }
    }
    gbar(cnt, (unsigned)NBLK * (++ep));   // h2 complete

    // ---------- phase C: logits partial (2 rows) + gumbel ; gh2_next ----------
    {
      float4 xr[4];
      #pragma unroll
      for (int it=0; it<4; ++it) xr[it] = *(const float4*)(h2g + 4*lane + 256*it);
      for (int j = wid; j < RPB; j += 4){
        float ah = 0.f;
        #pragma unroll
        for (int it=0; it<4; ++it){
          float4 w = *(const float4*)&sWhh2[j*HID_ + 4*lane + 256*it];
          ah += w.x*xr[it].x + w.y*xr[it].y + w.z*xr[it].z + w.w*xr[it].w;
        }
        #pragma unroll
        for (int m=32; m; m>>=1) ah += __shfl_xor(ah, m);
        if (lane == 0) sGh2[j] = ah + sBhh2[j];
      }
      if (wid < 2){
        const int q = sym*512 + (b<<1) + wid;
        const float* wr = Wa + (size_t)q * HID_;
        float acc = 0.f;
        #pragma unroll
        for (int it=0; it<4; ++it){
          float4 w = *(const float4*)(wr + 4*lane + 256*it);
          acc += w.x*xr[it].x + w.y*xr[it].y + w.z*xr[it].z + w.w*xr[it].w;
        }
        #pragma unroll
        for (int m=32; m; m>>=1) acc += __shfl_xor(acc, m);
        if (lane == 0) sLV[wid] = acc + ba[q] + gumbel_at(t, q);
      }
      __syncthreads();
      if (tid == 0){
        const int q0 = sym*512 + (b<<1);
        float v0 = sLV[0], v1 = sLV[1];
        if (v1 > v0){ pval[b] = v1; pidx[b] = q0 + 1; }
        else        { pval[b] = v0; pidx[b] = q0;     }
      }
    }
    gbar(cnt, (unsigned)NBLK * (++ep));   // partials complete

    // ---------- phase D: redundant global argmax + stack update ----------
    {
      float v  = pval[tid];
      int   ix = pidx[tid];
      #pragma unroll
      for (int m=32; m; m>>=1){
        float ov = __shfl_xor(v, m);
        int   oi = __shfl_xor(ix, m);
        if (ov > v || (ov == v && oi < ix)){ v = ov; ix = oi; }
      }
      if (lane == 0){ sRv[wid] = v; sRi[wid] = ix; }
      __syncthreads();
      if (tid == 0){
        float bv = sRv[0]; int bi = sRi[0];
        #pragma unroll
        for (int w=1; w<4; ++w){
          if (sRv[w] > bv || (sRv[w] == bv && sRi[w] < bi)){ bv = sRv[w]; bi = sRi[w]; }
        }
        const int action = bi;
        const int ch0 = ctab[2*action];
        const int ch1 = ctab[2*action + 1];
        sSym[idx] = (short)ch1; sAct[idx] = (short)action;
        int j1 = idx + 1; if (j1 > STK-1) j1 = STK-1;
        sSym[j1] = (short)ch0; sAct[j1] = (short)action;
        int np = idx + 2; if (np > STK) np = STK;
        sPtr = np; sPrev = action;
        if (b == 0) out[t] = (float)action;
      }
      __syncthreads();
    }
  }

  gbar(cnt, (unsigned)NBLK * (++ep));
  if (b == 0){
    for (int i = tid; i < HID_; i += NTHR){
      out[NSTEP + i]        = h1g[i];
      out[NSTEP + HID_ + i] = h2g[i];
    }
  }
}

extern "C" void kernel_launch(void* const* d_in, const int* in_sizes, int n_in,
                              void* d_out, int out_size, void* d_ws, size_t ws_size,
                              hipStream_t stream) {
  (void)in_sizes; (void)n_in; (void)out_size; (void)ws_size;
  const float* emb  = (const float*)d_in[0];
  const float* Wih1 = (const float*)d_in[1];
  const float* Whh1 = (const float*)d_in[2];
  const float* bih1 = (const float*)d_in[3];
  const float* bhh1 = (const float*)d_in[4];
  const float* Wih2 = (const float*)d_in[5];
  const float* Whh2 = (const float*)d_in[6];
  const float* bih2 = (const float*)d_in[7];
  const float* bhh2 = (const float*)d_in[8];
  const float* Wa   = (const float*)d_in[9];
  const float* ba   = (const float*)d_in[10];
  const float* h0   = (const float*)d_in[11];
  const int*   ctab = (const int*)d_in[12];
  float* out = (float*)d_out;

  char* ws = (char*)d_ws;
  unsigned* cnt = (unsigned*)ws;            // barrier counter @ 0
  float* h1g = (float*)(ws + 4096);         // 1024 f
  float* h2g = (float*)(ws + 8192);         // 1024 f
  float* pv  = (float*)(ws + 12288);        // 256 f
  int*   pi  = (int*)(ws + 13312);          // 256 i

  hipMemsetAsync(d_ws, 0, 4096, stream);    // zero barrier counter (ws is poisoned)
  tree_gen<<<NBLK, NTHR, 0, stream>>>(emb, Wih1, Whh1, bih1, bhh1, Wih2, Whh2,
                                      bih2, bhh2, Wa, ba, h0, ctab, out,
                                      h1g, h2g, pv, pi, cnt);
}

// Round 5
// 18268.599 us; speedup vs baseline: 2.7696x; 2.7696x over previous
//
#include <hip/hip_runtime.h>
#include <stdint.h>

// TreeGenerator: persistent kernel, 256 blocks x 256 thr, 1 block/CU.
// 3 fence-free grid barriers per expand step (sc0sc1 relaxed atomics, 2-level
// tree). Sticky dead-flag spin bail (~0.3s once, then sprint) -> never wedges.
// ws usage compacted to 12288 B (round-1 proven envelope was 14336 B).
// Whh1/Wih2/Whh2 LDS-resident; Wih1 rows register-resident; Wa/emb streamed.

#define NBLK   256
#define NTHR   256
#define HID_   1024
#define RPB    12      // gate rows per block (3 gates x 4 h-indices)
#define NSTEP  1024
#define STK    1028
#define NUMNT  16
#define JAX_PARTITIONABLE 1

__device__ __forceinline__ uint32_t rotl32(uint32_t v, int d){ return (v<<d)|(v>>(32-d)); }

__device__ __forceinline__ void tf2x32(uint32_t k0, uint32_t k1, uint32_t x0, uint32_t x1,
                                       uint32_t& o0, uint32_t& o1){
  uint32_t k2 = k0 ^ k1 ^ 0x1BD11BDAu;
  x0 += k0; x1 += k1;
  x0+=x1; x1=rotl32(x1,13); x1^=x0;
  x0+=x1; x1=rotl32(x1,15); x1^=x0;
  x0+=x1; x1=rotl32(x1,26); x1^=x0;
  x0+=x1; x1=rotl32(x1, 6); x1^=x0;
  x0+=k1; x1+=k2+1u;
  x0+=x1; x1=rotl32(x1,17); x1^=x0;
  x0+=x1; x1=rotl32(x1,29); x1^=x0;
  x0+=x1; x1=rotl32(x1,16); x1^=x0;
  x0+=x1; x1=rotl32(x1,24); x1^=x0;
  x0+=k2; x1+=k0+2u;
  x0+=x1; x1=rotl32(x1,13); x1^=x0;
  x0+=x1; x1=rotl32(x1,15); x1^=x0;
  x0+=x1; x1=rotl32(x1,26); x1^=x0;
  x0+=x1; x1=rotl32(x1, 6); x1^=x0;
  x0+=k0; x1+=k1+3u;
  x0+=x1; x1=rotl32(x1,17); x1^=x0;
  x0+=x1; x1=rotl32(x1,29); x1^=x0;
  x0+=x1; x1=rotl32(x1,16); x1^=x0;
  x0+=x1; x1=rotl32(x1,24); x1^=x0;
  x0+=k1; x1+=k2+4u;
  x0+=x1; x1=rotl32(x1,13); x1^=x0;
  x0+=x1; x1=rotl32(x1,15); x1^=x0;
  x0+=x1; x1=rotl32(x1,26); x1^=x0;
  x0+=x1; x1=rotl32(x1, 6); x1^=x0;
  x0+=k2; x1+=k0+5u;
  o0 = x0; o1 = x1;
}

__device__ __forceinline__ float gumbel_at(int t, int q){
  uint32_t fk0, fk1, a, c, bits;
  tf2x32(0u, 42u, 0u, (uint32_t)t, fk0, fk1);   // fold_in(key(42), t)
#if JAX_PARTITIONABLE
  tf2x32(fk0, fk1, 0u, (uint32_t)q, a, c);
  bits = a ^ c;
#else
  if (q < 4096){ tf2x32(fk0, fk1, (uint32_t)q, (uint32_t)(q+4096), a, c); bits = a; }
  else         { tf2x32(fk0, fk1, (uint32_t)(q-4096), (uint32_t)q, a, c); bits = c; }
#endif
  float f = __uint_as_float((bits >> 9) | 0x3f800000u) - 1.0f;
  float u = fmaxf(1.17549435e-38f, f);
  return -logf(-logf(u));
}

__device__ __forceinline__ float sigf(float x){ return 0.5f + 0.5f * tanhf(0.5f * x); }

// coherent (cross-XCD) access helpers: compile to sc0 sc1 global ops.
__device__ __forceinline__ float gload(const float* p){
  return __hip_atomic_load(p, __ATOMIC_RELAXED, __HIP_MEMORY_SCOPE_AGENT);
}
__device__ __forceinline__ float2 gload2(const float* p){
  union { unsigned long long u; float2 f; } v;
  v.u = __hip_atomic_load((const unsigned long long*)p, __ATOMIC_RELAXED,
                          __HIP_MEMORY_SCOPE_AGENT);
  return v.f;
}
__device__ __forceinline__ void gstore(float* p, float v){
  __hip_atomic_store(p, v, __ATOMIC_RELAXED, __HIP_MEMORY_SCOPE_AGENT);
}

__global__ __launch_bounds__(NTHR, 1)
void tree_gen(const float* __restrict__ emb,  const float* __restrict__ Wih1,
              const float* __restrict__ Whh1, const float* __restrict__ bih1,
              const float* __restrict__ bhh1, const float* __restrict__ Wih2,
              const float* __restrict__ Whh2, const float* __restrict__ bih2,
              const float* __restrict__ bhh2, const float* __restrict__ Wa,
              const float* __restrict__ ba,   const float* __restrict__ h0,
              const int* __restrict__ ctab,
              float* __restrict__ out,
              float* __restrict__ h1g, float* __restrict__ h2g,
              unsigned long long* __restrict__ winner,
              unsigned* __restrict__ gcnt, unsigned* __restrict__ root,
              unsigned* __restrict__ flag)
{
  __shared__ __align__(16) float sWhh1[RPB*HID_];   // 48 KB
  __shared__ __align__(16) float sWih2[RPB*HID_];   // 48 KB
  __shared__ __align__(16) float sWhh2[RPB*HID_];   // 48 KB
  __shared__ __align__(16) float sH[HID_];          // staged h vector (4 KB)
  __shared__ short sSym[STK];
  __shared__ short sAct[STK];
  __shared__ float sGh1[RPB], sGh2[RPB], sGi[RPB];
  __shared__ float sBih1[RPB], sBih2[RPB], sBhh1[RPB], sBhh2[RPB];
  __shared__ float sH1o[4], sH2o[4];
  __shared__ float sLV[2];
  __shared__ int   sPtr, sPrev;
  __shared__ int   sDead;

  const int tid  = threadIdx.x;
  const int b    = blockIdx.x;
  const int wid  = tid >> 6;
  const int lane = tid & 63;
  unsigned ep = 0;    // barrier epoch
  int eix = 0;        // expand-step counter (winner slot rotation)

  // fence-free 2-level grid barrier; sticky dead flag on timeout.
  auto gbar = [&](unsigned epoch){
    __syncthreads();
    if (tid == 0 && !sDead){
      asm volatile("s_waitcnt vmcnt(0)" ::: "memory");
      unsigned* gc = gcnt + ((b >> 3) << 4);   // 32 groups of 8 blocks, 64B apart
      unsigned o = __hip_atomic_fetch_add(gc, 1u, __ATOMIC_RELAXED, __HIP_MEMORY_SCOPE_AGENT);
      if (o == (epoch << 3) - 1u){             // last of my 8-block group
        unsigned r = __hip_atomic_fetch_add(root, 1u, __ATOMIC_RELAXED, __HIP_MEMORY_SCOPE_AGENT);
        if (r == (epoch << 5) - 1u)            // last of 32 groups
          __hip_atomic_store(flag, epoch, __ATOMIC_RELAXED, __HIP_MEMORY_SCOPE_AGENT);
      }
      unsigned tries = 0;
      while (__hip_atomic_load(flag, __ATOMIC_RELAXED, __HIP_MEMORY_SCOPE_AGENT) < epoch){
        __builtin_amdgcn_s_sleep(2);
        if (++tries > 2000000u){ sDead = 1; break; }  // ~0.3s, then sprint
      }
    }
    __syncthreads();
  };

  // ---- stage this block's 12 rows of each recurrent matrix into LDS ----
  for (int j = 0; j < RPB; ++j){
    const int r = (j >> 2) * HID_ + (b << 2) + (j & 3);
    const float* a1 = Whh1 + (size_t)r * HID_;
    const float* a2 = Wih2 + (size_t)r * HID_;
    const float* a3 = Whh2 + (size_t)r * HID_;
    for (int c = tid * 4; c < HID_; c += NTHR * 4){
      *(float4*)&sWhh1[j*HID_ + c] = *(const float4*)(a1 + c);
      *(float4*)&sWih2[j*HID_ + c] = *(const float4*)(a2 + c);
      *(float4*)&sWhh2[j*HID_ + c] = *(const float4*)(a3 + c);
    }
  }
  if (tid < RPB){
    const int r = (tid >> 2) * HID_ + (b << 2) + (tid & 3);
    sBih1[tid] = bih1[r]; sBih2[tid] = bih2[r];
    sBhh1[tid] = bhh1[r]; sBhh2[tid] = bhh2[r];
  }
  if (tid == 0){ sSym[0] = 0; sAct[0] = -1; sPtr = 1; sPrev = -1; sDead = 0; }
  if (tid < 4){
    float v1 = h0[(b<<2)+tid];
    float v2 = h0[HID_+(b<<2)+tid];
    sH1o[tid] = v1; sH2o[tid] = v2;
    gstore(h1g + (b<<2)+tid, v1);
    gstore(h2g + (b<<2)+tid, v2);
  }

  // ---- pin this block's 12 Wih1 rows in registers (3 rows/wave, 96 VGPR) ----
  float4 wA[3][8];
  #pragma unroll
  for (int jj = 0; jj < 3; ++jj){
    const int j = wid + 4*jj;
    const int r = (j >> 2) * HID_ + (b << 2) + (j & 3);
    const float* wr = Wih1 + (size_t)r * 2048 + 4*lane;
    #pragma unroll
    for (int it = 0; it < 4; ++it){
      wA[jj][it]     = *(const float4*)(wr + 256*it);
      wA[jj][4 + it] = *(const float4*)(wr + 1024 + 256*it);
    }
  }
  __syncthreads();

  // ---- initial gh1 = Whh1@h0[0]+bhh1 ; gh2 = Whh2@h0[1]+bhh2 (local rows) ----
  {
    float4 x1[4], x2[4];
    #pragma unroll
    for (int it=0; it<4; ++it){
      x1[it] = *(const float4*)(h0 + 4*lane + 256*it);
      x2[it] = *(const float4*)(h0 + HID_ + 4*lane + 256*it);
    }
    #pragma unroll
    for (int jj=0; jj<3; ++jj){
      const int j = wid + 4*jj;
      float a1 = 0.f, a2 = 0.f;
      #pragma unroll
      for (int it=0; it<4; ++it){
        float4 w1 = *(const float4*)&sWhh1[j*HID_ + 4*lane + 256*it];
        float4 w2 = *(const float4*)&sWhh2[j*HID_ + 4*lane + 256*it];
        a1 += w1.x*x1[it].x + w1.y*x1[it].y + w1.z*x1[it].z + w1.w*x1[it].w;
        a2 += w2.x*x2[it].x + w2.y*x2[it].y + w2.z*x2[it].z + w2.w*x2[it].w;
      }
      #pragma unroll
      for (int m=32; m; m>>=1){ a1 += __shfl_xor(a1, m); a2 += __shfl_xor(a2, m); }
      if (lane == 0){ sGh1[j] = a1 + sBhh1[j]; sGh2[j] = a2 + sBhh2[j]; }
    }
  }
  __syncthreads();

  for (int t = 0; t < NSTEP; ++t){
    const int  ptr    = sPtr;
    const bool active = ptr > 0;
    const int  idx    = active ? (ptr - 1) : 0;
    const int  sym    = sSym[idx];
    const int  parent = sAct[idx];
    const int  prev   = sPrev;
    const bool expand = active && (sym < NUMNT);

    if (!expand){
      __syncthreads();
      if (tid == 0){
        if (active) sPtr = ptr - 1;
        if (b == 0) out[t] = -1.0f;
      }
      __syncthreads();
      continue;
    }

    // ---------- phase A: gi1 = Wih1(regs) @ [emb[prev+1]; emb[parent+1]] ; h1 ----------
    {
      const float* embP = emb + (size_t)(prev + 1) * HID_ + 4*lane;
      const float* embQ = emb + (size_t)(parent + 1) * HID_ + 4*lane;
      float4 xp[4], xq[4];
      #pragma unroll
      for (int it=0; it<4; ++it){
        xp[it] = *(const float4*)(embP + 256*it);
        xq[it] = *(const float4*)(embQ + 256*it);
      }
      #pragma unroll
      for (int jj=0; jj<3; ++jj){
        float acc = 0.f;
        #pragma unroll
        for (int it=0; it<4; ++it){
          acc += wA[jj][it].x*xp[it].x + wA[jj][it].y*xp[it].y
               + wA[jj][it].z*xp[it].z + wA[jj][it].w*xp[it].w;
        }
        #pragma unroll
        for (int it=0; it<4; ++it){
          acc += wA[jj][4+it].x*xq[it].x + wA[jj][4+it].y*xq[it].y
               + wA[jj][4+it].z*xq[it].z + wA[jj][4+it].w*xq[it].w;
        }
        #pragma unroll
        for (int m=32; m; m>>=1) acc += __shfl_xor(acc, m);
        if (lane == 0) sGi[wid + 4*jj] = acc + sBih1[wid + 4*jj];
      }
      __syncthreads();
      if (tid < 4){
        float rr = sigf(sGi[tid]    + sGh1[tid]);
        float zz = sigf(sGi[4+tid]  + sGh1[4+tid]);
        float nn = tanhf(sGi[8+tid] + rr * sGh1[8+tid]);
        float nh = (1.f - zz)*nn + zz*sH1o[tid];
        sH1o[tid] = nh;
        gstore(h1g + (b<<2)+tid, nh);
      }
    }
    gbar(++ep);   // h1 complete

    // ---------- phase B: stage h1 ; gi2 = Wih2@h1 -> h2 ; gh1_next = Whh1@h1 ----------
    {
      // rotate winner slots: zero slot (eix+2)&3 (safe: last read at D(eix-2)
      // before everyone's B1(eix-1); next write at C(eix+2) after B2(eix+2)).
      if (b == 0 && tid == 0)
        __hip_atomic_store(winner + ((eix + 2) & 3), 0ull,
                           __ATOMIC_RELAXED, __HIP_MEMORY_SCOPE_AGENT);
      {
        const int c = tid << 2;
        float2 lo = gload2(h1g + c);
        float2 hi = gload2(h1g + c + 2);
        *(float4*)&sH[c] = make_float4(lo.x, lo.y, hi.x, hi.y);
      }
      __syncthreads();
      #pragma unroll
      for (int jj=0; jj<3; ++jj){
        const int j = wid + 4*jj;
        float ai = 0.f, ah = 0.f;
        #pragma unroll
        for (int it=0; it<4; ++it){
          float4 xr = *(const float4*)&sH[4*lane + 256*it];
          float4 w2 = *(const float4*)&sWih2[j*HID_ + 4*lane + 256*it];
          float4 w1 = *(const float4*)&sWhh1[j*HID_ + 4*lane + 256*it];
          ai += w2.x*xr.x + w2.y*xr.y + w2.z*xr.z + w2.w*xr.w;
          ah += w1.x*xr.x + w1.y*xr.y + w1.z*xr.z + w1.w*xr.w;
        }
        #pragma unroll
        for (int m=32; m; m>>=1){ ai += __shfl_xor(ai, m); ah += __shfl_xor(ah, m); }
        if (lane == 0){ sGi[j] = ai + sBih2[j]; sGh1[j] = ah + sBhh1[j]; }
      }
      __syncthreads();
      if (tid < 4){
        float rr = sigf(sGi[tid]    + sGh2[tid]);
        float zz = sigf(sGi[4+tid]  + sGh2[4+tid]);
        float nn = tanhf(sGi[8+tid] + rr * sGh2[8+tid]);
        float nh = (1.f - zz)*nn + zz*sH2o[tid];
        sH2o[tid] = nh;
        gstore(h2g + (b<<2)+tid, nh);
      }
    }
    gbar(++ep);   // h2 complete

    // ---------- phase C: stage h2 ; gh2_next ; 2 logit rows + gumbel -> atomic max ----------
    {
      {
        const int c = tid << 2;
        float2 lo = gload2(h2g + c);
        float2 hi = gload2(h2g + c + 2);
        *(float4*)&sH[c] = make_float4(lo.x, lo.y, hi.x, hi.y);
      }
      __syncthreads();
      #pragma unroll
      for (int jj=0; jj<3; ++jj){
        const int j = wid + 4*jj;
        float ah = 0.f;
        #pragma unroll
        for (int it=0; it<4; ++it){
          float4 xr = *(const float4*)&sH[4*lane + 256*it];
          float4 w  = *(const float4*)&sWhh2[j*HID_ + 4*lane + 256*it];
          ah += w.x*xr.x + w.y*xr.y + w.z*xr.z + w.w*xr.w;
        }
        #pragma unroll
        for (int m=32; m; m>>=1) ah += __shfl_xor(ah, m);
        if (lane == 0) sGh2[j] = ah + sBhh2[j];
      }
      if (wid < 2){
        const int q = sym*512 + (b<<1) + wid;
        const float* wr = Wa + (size_t)q * HID_ + 4*lane;
        float acc = 0.f;
        #pragma unroll
        for (int it=0; it<4; ++it){
          float4 xr = *(const float4*)&sH[4*lane + 256*it];
          float4 w  = *(const float4*)(wr + 256*it);
          acc += w.x*xr.x + w.y*xr.y + w.z*xr.z + w.w*xr.w;
        }
        #pragma unroll
        for (int m=32; m; m>>=1) acc += __shfl_xor(acc, m);
        if (lane == 0) sLV[wid] = acc + ba[q] + gumbel_at(t, q);
      }
      __syncthreads();
      if (tid == 0){
        const int q0 = sym*512 + (b<<1);
        float v; int q;
        if (sLV[1] > sLV[0]){ v = sLV[1]; q = q0 + 1; }
        else                { v = sLV[0]; q = q0;     }
        unsigned ub   = __float_as_uint(v);
        unsigned mono = (ub & 0x80000000u) ? ~ub : (ub | 0x80000000u);
        unsigned long long key = ((unsigned long long)mono << 13)
                               | (unsigned long long)(8191 - q);
        __hip_atomic_fetch_max(winner + (eix & 3), key,
                               __ATOMIC_RELAXED, __HIP_MEMORY_SCOPE_AGENT);
      }
    }
    gbar(++ep);   // all partial maxes merged

    // ---------- phase D: read winner, update replicated stack ----------
    if (tid == 0){
      unsigned long long w = __hip_atomic_load(winner + (eix & 3), __ATOMIC_RELAXED,
                                               __HIP_MEMORY_SCOPE_AGENT);
      const int action = 8191 - (int)(w & 8191ull);
      const int ch0 = ctab[2*action];
      const int ch1 = ctab[2*action + 1];
      sSym[idx] = (short)ch1; sAct[idx] = (short)action;
      int j1 = idx + 1; if (j1 > STK-1) j1 = STK-1;
      sSym[j1] = (short)ch0; sAct[j1] = (short)action;
      int np = idx + 2; if (np > STK) np = STK;
      sPtr = np; sPrev = action;
      if (b == 0) out[t] = (float)action;
    }
    __syncthreads();
    ++eix;
  }

  if (b == 0){
    for (int i = tid; i < HID_; i += NTHR){
      out[NSTEP + i]        = gload(h1g + i);
      out[NSTEP + HID_ + i] = gload(h2g + i);
    }
  }
}

extern "C" void kernel_launch(void* const* d_in, const int* in_sizes, int n_in,
                              void* d_out, int out_size, void* d_ws, size_t ws_size,
                              hipStream_t stream) {
  (void)in_sizes; (void)n_in; (void)out_size; (void)ws_size;
  const float* emb  = (const float*)d_in[0];
  const float* Wih1 = (const float*)d_in[1];
  const float* Whh1 = (const float*)d_in[2];
  const float* bih1 = (const float*)d_in[3];
  const float* bhh1 = (const float*)d_in[4];
  const float* Wih2 = (const float*)d_in[5];
  const float* Whh2 = (const float*)d_in[6];
  const float* bih2 = (const float*)d_in[7];
  const float* bhh2 = (const float*)d_in[8];
  const float* Wa   = (const float*)d_in[9];
  const float* ba   = (const float*)d_in[10];
  const float* h0   = (const float*)d_in[11];
  const int*   ctab = (const int*)d_in[12];
  float* out = (float*)d_out;

  // Compact ws layout: 12288 B total (round-1 proven envelope: 14336 B).
  char* ws = (char*)d_ws;
  unsigned* gcnt = (unsigned*)ws;                          // 32 counters, 64B apart: [0,2048)
  unsigned* root = (unsigned*)(ws + 2048);                 // own line
  unsigned* flag = (unsigned*)(ws + 2112);                 // own line
  unsigned long long* winner = (unsigned long long*)(ws + 2176);  // u64[4] rotating
  float* h1g = (float*)(ws + 4096);                        // 1024 f32
  float* h2g = (float*)(ws + 8192);                        // 1024 f32

  hipMemsetAsync(d_ws, 0, 4096, stream);   // zero counters + flag + winner slots
  tree_gen<<<NBLK, NTHR, 0, stream>>>(emb, Wih1, Whh1, bih1, bhh1, Wih2, Whh2,
                                      bih2, bhh2, Wa, ba, h0, ctab, out,
                                      h1g, h2g, winner, gcnt, root, flag);
}

// Round 6
// 14625.081 us; speedup vs baseline: 3.4596x; 1.2491x over previous
//
#include <hip/hip_runtime.h>
#include <stdint.h>

// TreeGenerator: persistent kernel, 256 blocks x 256 thr, 1 block/CU.
// XCD-hierarchical fence-free grid barrier:
//   arrival  : local-L2 (non-sc1) fetch_add on per-XCD counter (xcc from s_getreg)
//   cross-die: last-of-XCD posts arr8[xcc]=ep (agent) and polls all 8 (agent)
//   release  : local flag, polled via local-L2 CAS (never L1-cacheable)
// Group sizes measured at runtime (no blockIdx->XCD assumption). Bounded spins
// + sticky dead flag -> worst case wrong answer in ~1s, never a wedged GPU.
// Whh1/Wih2/Whh2 LDS-resident; Wih1 register-resident; Wa rows prefetched.

#define NBLK   256
#define NTHR   256
#define HID_   1024
#define RPB    12      // gate rows per block (3 gates x 4 h-indices)
#define NSTEP  1024
#define STK    1028
#define NUMNT  16
#define JAX_PARTITIONABLE 1

__device__ __forceinline__ uint32_t rotl32(uint32_t v, int d){ return (v<<d)|(v>>(32-d)); }

__device__ __forceinline__ void tf2x32(uint32_t k0, uint32_t k1, uint32_t x0, uint32_t x1,
                                       uint32_t& o0, uint32_t& o1){
  uint32_t k2 = k0 ^ k1 ^ 0x1BD11BDAu;
  x0 += k0; x1 += k1;
  x0+=x1; x1=rotl32(x1,13); x1^=x0;
  x0+=x1; x1=rotl32(x1,15); x1^=x0;
  x0+=x1; x1=rotl32(x1,26); x1^=x0;
  x0+=x1; x1=rotl32(x1, 6); x1^=x0;
  x0+=k1; x1+=k2+1u;
  x0+=x1; x1=rotl32(x1,17); x1^=x0;
  x0+=x1; x1=rotl32(x1,29); x1^=x0;
  x0+=x1; x1=rotl32(x1,16); x1^=x0;
  x0+=x1; x1=rotl32(x1,24); x1^=x0;
  x0+=k2; x1+=k0+2u;
  x0+=x1; x1=rotl32(x1,13); x1^=x0;
  x0+=x1; x1=rotl32(x1,15); x1^=x0;
  x0+=x1; x1=rotl32(x1,26); x1^=x0;
  x0+=x1; x1=rotl32(x1, 6); x1^=x0;
  x0+=k0; x1+=k1+3u;
  x0+=x1; x1=rotl32(x1,17); x1^=x0;
  x0+=x1; x1=rotl32(x1,29); x1^=x0;
  x0+=x1; x1=rotl32(x1,16); x1^=x0;
  x0+=x1; x1=rotl32(x1,24); x1^=x0;
  x0+=k1; x1+=k2+4u;
  x0+=x1; x1=rotl32(x1,13); x1^=x0;
  x0+=x1; x1=rotl32(x1,15); x1^=x0;
  x0+=x1; x1=rotl32(x1,26); x1^=x0;
  x0+=x1; x1=rotl32(x1, 6); x1^=x0;
  x0+=k2; x1+=k0+5u;
  o0 = x0; o1 = x1;
}

__device__ __forceinline__ float gumbel_at(int t, int q){
  uint32_t fk0, fk1, a, c, bits;
  tf2x32(0u, 42u, 0u, (uint32_t)t, fk0, fk1);   // fold_in(key(42), t)
#if JAX_PARTITIONABLE
  tf2x32(fk0, fk1, 0u, (uint32_t)q, a, c);
  bits = a ^ c;
#else
  if (q < 4096){ tf2x32(fk0, fk1, (uint32_t)q, (uint32_t)(q+4096), a, c); bits = a; }
  else         { tf2x32(fk0, fk1, (uint32_t)(q-4096), (uint32_t)q, a, c); bits = c; }
#endif
  float f = __uint_as_float((bits >> 9) | 0x3f800000u) - 1.0f;
  float u = fmaxf(1.17549435e-38f, f);
  return -logf(-logf(u));
}

__device__ __forceinline__ float sigf(float x){ return 0.5f + 0.5f * tanhf(0.5f * x); }

// agent (cross-XCD, sc0sc1) access helpers
__device__ __forceinline__ float gload(const float* p){
  return __hip_atomic_load(p, __ATOMIC_RELAXED, __HIP_MEMORY_SCOPE_AGENT);
}
__device__ __forceinline__ float2 gload2(const float* p){
  union { unsigned long long u; float2 f; } v;
  v.u = __hip_atomic_load((const unsigned long long*)p, __ATOMIC_RELAXED,
                          __HIP_MEMORY_SCOPE_AGENT);
  return v.f;
}
__device__ __forceinline__ void gstore(float* p, float v){
  __hip_atomic_store(p, v, __ATOMIC_RELAXED, __HIP_MEMORY_SCOPE_AGENT);
}
// local-L2 (same-XCD) poll: CAS with impossible expected value — always an
// RMW at L2 (cannot be legalized into an L1-cacheable plain load).
__device__ __forceinline__ unsigned lpoll(unsigned* p){
  unsigned e = 0xFFFFFFFFu;
  __hip_atomic_compare_exchange_strong(p, &e, 0xFFFFFFFFu,
      __ATOMIC_RELAXED, __ATOMIC_RELAXED, __HIP_MEMORY_SCOPE_WORKGROUP);
  return e;
}

__global__ __launch_bounds__(NTHR, 1)
void tree_gen(const float* __restrict__ emb,  const float* __restrict__ Wih1,
              const float* __restrict__ Whh1, const float* __restrict__ bih1,
              const float* __restrict__ bhh1, const float* __restrict__ Wih2,
              const float* __restrict__ Whh2, const float* __restrict__ bih2,
              const float* __restrict__ bhh2, const float* __restrict__ Wa,
              const float* __restrict__ ba,   const float* __restrict__ h0,
              const int* __restrict__ ctab,
              float* __restrict__ out,
              float* __restrict__ h1g, float* __restrict__ h2g,
              unsigned long long* __restrict__ winner,
              unsigned* __restrict__ ctrl)
{
  __shared__ __align__(16) float sWhh1[RPB*HID_];   // 48 KB
  __shared__ __align__(16) float sWih2[RPB*HID_];   // 48 KB
  __shared__ __align__(16) float sWhh2[RPB*HID_];   // 48 KB
  __shared__ __align__(16) float sH[HID_];          // staged h vector (4 KB)
  __shared__ short sSym[STK];
  __shared__ short sAct[STK];
  __shared__ float sGh1[RPB], sGh2[RPB], sGi[RPB];
  __shared__ float sBih1[RPB], sBih2[RPB], sBhh1[RPB], sBhh2[RPB];
  __shared__ float sH1o[4], sH2o[4];
  __shared__ float sLV[2];
  __shared__ int   sPtr, sPrev;
  __shared__ int   sDead;

  const int tid  = threadIdx.x;
  const int b    = blockIdx.x;
  const int wid  = tid >> 6;
  const int lane = tid & 63;
  unsigned ep = 0;    // barrier epoch
  int eix = 0;        // expand-step counter (winner slot rotation)

  // ---- control layout inside ctrl (all zeroed by host memset) ----
  unsigned xcc;
  asm volatile("s_getreg_b32 %0, hwreg(HW_REG_XCC_ID)" : "=s"(xcc));
  xcc &= 7u;
  unsigned* leaf     = ctrl + xcc*32;          // [0,1024): 8 x 128B, LOCAL scope only
  unsigned* lfl      = ctrl + 256 + xcc*32;    // [1024,2048): 8 x 128B, LOCAL scope only
  unsigned* arr8     = ctrl + 512;             // [2048,2080): u32[8], AGENT scope only
  unsigned* xcdCount = ctrl + 544;             // [2176/4]: u32[8], AGENT
  unsigned* initCnt  = ctrl + 576;             // AGENT
  unsigned* initFlag = ctrl + 608;             // AGENT
  unsigned myCnt = 0;

  // ---- setup pass: measure per-XCD group sizes, one flat agent barrier ----
  if (tid == 0){
    sSym[0] = 0; sAct[0] = -1; sPtr = 1; sPrev = -1; sDead = 0;
    __hip_atomic_fetch_add(&xcdCount[xcc], 1u, __ATOMIC_RELAXED, __HIP_MEMORY_SCOPE_AGENT);
    asm volatile("s_waitcnt vmcnt(0)" ::: "memory");
    unsigned o = __hip_atomic_fetch_add(initCnt, 1u, __ATOMIC_RELAXED, __HIP_MEMORY_SCOPE_AGENT);
    if (o == NBLK - 1u)
      __hip_atomic_store(initFlag, 1u, __ATOMIC_RELAXED, __HIP_MEMORY_SCOPE_AGENT);
    unsigned tries = 0;
    while (__hip_atomic_load(initFlag, __ATOMIC_RELAXED, __HIP_MEMORY_SCOPE_AGENT) < 1u){
      __builtin_amdgcn_s_sleep(2);
      if (++tries > 2000000u){ sDead = 1; break; }
    }
    myCnt = __hip_atomic_load(&xcdCount[xcc], __ATOMIC_RELAXED, __HIP_MEMORY_SCOPE_AGENT);
  }

  // XCD-hierarchical fence-free grid barrier; sticky dead flag on timeout.
  auto gbar = [&](unsigned epoch){
    __syncthreads();
    if (tid == 0 && !sDead){
      asm volatile("s_waitcnt vmcnt(0)" ::: "memory");
      unsigned o = __hip_atomic_fetch_add(leaf, 1u, __ATOMIC_RELAXED,
                                          __HIP_MEMORY_SCOPE_WORKGROUP);   // local L2
      if (o == myCnt * epoch - 1u){
        // I'm this XCD's relay for this barrier
        __hip_atomic_store(&arr8[xcc], epoch, __ATOMIC_RELAXED, __HIP_MEMORY_SCOPE_AGENT);
        unsigned tries = 0;
        for (int x = 0; x < 8; ){
          unsigned v = __hip_atomic_load(&arr8[x], __ATOMIC_RELAXED, __HIP_MEMORY_SCOPE_AGENT);
          if (v >= epoch){ ++x; continue; }
          __builtin_amdgcn_s_sleep(1);
          if (++tries > 2000000u){ sDead = 1; break; }
        }
        __hip_atomic_store(lfl, epoch, __ATOMIC_RELAXED, __HIP_MEMORY_SCOPE_WORKGROUP);
        asm volatile("s_waitcnt vmcnt(0)" ::: "memory");
      } else {
        unsigned tries = 0;
        while (lpoll(lfl) < epoch){
          __builtin_amdgcn_s_sleep(1);
          if (++tries > 4000000u){ sDead = 1; break; }
        }
      }
    }
    __syncthreads();
  };

  // ---- stage this block's 12 rows of each recurrent matrix into LDS ----
  for (int j = 0; j < RPB; ++j){
    const int r = (j >> 2) * HID_ + (b << 2) + (j & 3);
    const float* a1 = Whh1 + (size_t)r * HID_;
    const float* a2 = Wih2 + (size_t)r * HID_;
    const float* a3 = Whh2 + (size_t)r * HID_;
    for (int c = tid * 4; c < HID_; c += NTHR * 4){
      *(float4*)&sWhh1[j*HID_ + c] = *(const float4*)(a1 + c);
      *(float4*)&sWih2[j*HID_ + c] = *(const float4*)(a2 + c);
      *(float4*)&sWhh2[j*HID_ + c] = *(const float4*)(a3 + c);
    }
  }
  if (tid < RPB){
    const int r = (tid >> 2) * HID_ + (b << 2) + (tid & 3);
    sBih1[tid] = bih1[r]; sBih2[tid] = bih2[r];
    sBhh1[tid] = bhh1[r]; sBhh2[tid] = bhh2[r];
  }
  if (tid < 4){
    float v1 = h0[(b<<2)+tid];
    float v2 = h0[HID_+(b<<2)+tid];
    sH1o[tid] = v1; sH2o[tid] = v2;
    gstore(h1g + (b<<2)+tid, v1);
    gstore(h2g + (b<<2)+tid, v2);
  }

  // ---- pin this block's 12 Wih1 rows in registers (3 rows/wave, 96 VGPR) ----
  float4 wA[3][8];
  #pragma unroll
  for (int jj = 0; jj < 3; ++jj){
    const int j = wid + 4*jj;
    const int r = (j >> 2) * HID_ + (b << 2) + (j & 3);
    const float* wr = Wih1 + (size_t)r * 2048 + 4*lane;
    #pragma unroll
    for (int it = 0; it < 4; ++it){
      wA[jj][it]     = *(const float4*)(wr + 256*it);
      wA[jj][4 + it] = *(const float4*)(wr + 1024 + 256*it);
    }
  }
  __syncthreads();

  // ---- initial gh1 = Whh1@h0[0]+bhh1 ; gh2 = Whh2@h0[1]+bhh2 (local rows) ----
  {
    float4 x1[4], x2[4];
    #pragma unroll
    for (int it=0; it<4; ++it){
      x1[it] = *(const float4*)(h0 + 4*lane + 256*it);
      x2[it] = *(const float4*)(h0 + HID_ + 4*lane + 256*it);
    }
    #pragma unroll
    for (int jj=0; jj<3; ++jj){
      const int j = wid + 4*jj;
      float a1 = 0.f, a2 = 0.f;
      #pragma unroll
      for (int it=0; it<4; ++it){
        float4 w1 = *(const float4*)&sWhh1[j*HID_ + 4*lane + 256*it];
        float4 w2 = *(const float4*)&sWhh2[j*HID_ + 4*lane + 256*it];
        a1 += w1.x*x1[it].x + w1.y*x1[it].y + w1.z*x1[it].z + w1.w*x1[it].w;
        a2 += w2.x*x2[it].x + w2.y*x2[it].y + w2.z*x2[it].z + w2.w*x2[it].w;
      }
      #pragma unroll
      for (int m=32; m; m>>=1){ a1 += __shfl_xor(a1, m); a2 += __shfl_xor(a2, m); }
      if (lane == 0){ sGh1[j] = a1 + sBhh1[j]; sGh2[j] = a2 + sBhh2[j]; }
    }
  }
  __syncthreads();

  for (int t = 0; t < NSTEP; ++t){
    const int  ptr    = sPtr;
    const bool active = ptr > 0;
    const int  idx    = active ? (ptr - 1) : 0;
    const int  sym    = sSym[idx];
    const int  parent = sAct[idx];
    const int  prev   = sPrev;
    const bool expand = active && (sym < NUMNT);

    if (!expand){
      __syncthreads();
      if (tid == 0){
        if (active) sPtr = ptr - 1;
        if (b == 0) out[t] = -1.0f;
      }
      __syncthreads();
      continue;
    }

    // ---- step-start prefetch: Wa rows + bias + gumbel for phase C (sym known) ----
    float4 wv[4]; float bq = 0.f, gmb = 0.f; int q = 0;
    if (wid < 2){
      q = sym*512 + (b<<1) + wid;
      const float* wr = Wa + (size_t)q * HID_ + 4*lane;
      #pragma unroll
      for (int it=0; it<4; ++it) wv[it] = *(const float4*)(wr + 256*it);
      bq  = ba[q];
      gmb = gumbel_at(t, q);        // independent of h2 — off the critical path
    }

    // ---------- phase A: gi1 = Wih1(regs) @ [emb[prev+1]; emb[parent+1]] ; h1 ----------
    {
      const float* embP = emb + (size_t)(prev + 1) * HID_ + 4*lane;
      const float* embQ = emb + (size_t)(parent + 1) * HID_ + 4*lane;
      float4 xp[4], xq[4];
      #pragma unroll
      for (int it=0; it<4; ++it){
        xp[it] = *(const float4*)(embP + 256*it);
        xq[it] = *(const float4*)(embQ + 256*it);
      }
      #pragma unroll
      for (int jj=0; jj<3; ++jj){
        float acc = 0.f;
        #pragma unroll
        for (int it=0; it<4; ++it){
          acc += wA[jj][it].x*xp[it].x + wA[jj][it].y*xp[it].y
               + wA[jj][it].z*xp[it].z + wA[jj][it].w*xp[it].w;
        }
        #pragma unroll
        for (int it=0; it<4; ++it){
          acc += wA[jj][4+it].x*xq[it].x + wA[jj][4+it].y*xq[it].y
               + wA[jj][4+it].z*xq[it].z + wA[jj][4+it].w*xq[it].w;
        }
        #pragma unroll
        for (int m=32; m; m>>=1) acc += __shfl_xor(acc, m);
        if (lane == 0) sGi[wid + 4*jj] = acc + sBih1[wid + 4*jj];
      }
      __syncthreads();
      if (tid < 4){
        float rr = sigf(sGi[tid]    + sGh1[tid]);
        float zz = sigf(sGi[4+tid]  + sGh1[4+tid]);
        float nn = tanhf(sGi[8+tid] + rr * sGh1[8+tid]);
        float nh = (1.f - zz)*nn + zz*sH1o[tid];
        sH1o[tid] = nh;
        gstore(h1g + (b<<2)+tid, nh);
      }
    }
    gbar(++ep);   // h1 complete

    // ---------- phase B: stage h1 ; gi2 = Wih2@h1 -> h2 ; gh1_next = Whh1@h1 ----------
    {
      // rotate winner slots: zero slot (eix+2)&3 (safe: last read at D(eix-2),
      // next write at C(eix+2)).
      if (b == 0 && tid == 0)
        __hip_atomic_store(winner + ((eix + 2) & 3), 0ull,
                           __ATOMIC_RELAXED, __HIP_MEMORY_SCOPE_AGENT);
      {
        const int c = tid << 2;
        float2 lo = gload2(h1g + c);
        float2 hi = gload2(h1g + c + 2);
        *(float4*)&sH[c] = make_float4(lo.x, lo.y, hi.x, hi.y);
      }
      __syncthreads();
      #pragma unroll
      for (int jj=0; jj<3; ++jj){
        const int j = wid + 4*jj;
        float ai = 0.f, ah = 0.f;
        #pragma unroll
        for (int it=0; it<4; ++it){
          float4 xr = *(const float4*)&sH[4*lane + 256*it];
          float4 w2 = *(const float4*)&sWih2[j*HID_ + 4*lane + 256*it];
          float4 w1 = *(const float4*)&sWhh1[j*HID_ + 4*lane + 256*it];
          ai += w2.x*xr.x + w2.y*xr.y + w2.z*xr.z + w2.w*xr.w;
          ah += w1.x*xr.x + w1.y*xr.y + w1.z*xr.z + w1.w*xr.w;
        }
        #pragma unroll
        for (int m=32; m; m>>=1){ ai += __shfl_xor(ai, m); ah += __shfl_xor(ah, m); }
        if (lane == 0){ sGi[j] = ai + sBih2[j]; sGh1[j] = ah + sBhh1[j]; }
      }
      __syncthreads();
      if (tid < 4){
        float rr = sigf(sGi[tid]    + sGh2[tid]);
        float zz = sigf(sGi[4+tid]  + sGh2[4+tid]);
        float nn = tanhf(sGi[8+tid] + rr * sGh2[8+tid]);
        float nh = (1.f - zz)*nn + zz*sH2o[tid];
        sH2o[tid] = nh;
        gstore(h2g + (b<<2)+tid, nh);
      }
    }
    gbar(++ep);   // h2 complete

    // ---------- phase C: stage h2 ; gh2_next ; 2 logit rows (prefetched) -> atomic max ----------
    {
      {
        const int c = tid << 2;
        float2 lo = gload2(h2g + c);
        float2 hi = gload2(h2g + c + 2);
        *(float4*)&sH[c] = make_float4(lo.x, lo.y, hi.x, hi.y);
      }
      __syncthreads();
      #pragma unroll
      for (int jj=0; jj<3; ++jj){
        const int j = wid + 4*jj;
        float ah = 0.f;
        #pragma unroll
        for (int it=0; it<4; ++it){
          float4 xr = *(const float4*)&sH[4*lane + 256*it];
          float4 w  = *(const float4*)&sWhh2[j*HID_ + 4*lane + 256*it];
          ah += w.x*xr.x + w.y*xr.y + w.z*xr.z + w.w*xr.w;
        }
        #pragma unroll
        for (int m=32; m; m>>=1) ah += __shfl_xor(ah, m);
        if (lane == 0) sGh2[j] = ah + sBhh2[j];
      }
      if (wid < 2){
        float acc = 0.f;
        #pragma unroll
        for (int it=0; it<4; ++it){
          float4 xr = *(const float4*)&sH[4*lane + 256*it];
          acc += wv[it].x*xr.x + wv[it].y*xr.y + wv[it].z*xr.z + wv[it].w*xr.w;
        }
        #pragma unroll
        for (int m=32; m; m>>=1) acc += __shfl_xor(acc, m);
        if (lane == 0) sLV[wid] = acc + bq + gmb;
      }
      __syncthreads();
      if (tid == 0){
        const int q0 = sym*512 + (b<<1);
        float v; int qq;
        if (sLV[1] > sLV[0]){ v = sLV[1]; qq = q0 + 1; }
        else                { v = sLV[0]; qq = q0;     }
        unsigned ub   = __float_as_uint(v);
        unsigned mono = (ub & 0x80000000u) ? ~ub : (ub | 0x80000000u);
        unsigned long long key = ((unsigned long long)mono << 13)
                               | (unsigned long long)(8191 - qq);
        __hip_atomic_fetch_max(winner + (eix & 3), key,
                               __ATOMIC_RELAXED, __HIP_MEMORY_SCOPE_AGENT);
      }
    }
    gbar(++ep);   // all partial maxes merged

    // ---------- phase D: read winner, update replicated stack ----------
    if (tid == 0){
      unsigned long long w = __hip_atomic_load(winner + (eix & 3), __ATOMIC_RELAXED,
                                               __HIP_MEMORY_SCOPE_AGENT);
      const int action = 8191 - (int)(w & 8191ull);
      const int ch0 = ctab[2*action];
      const int ch1 = ctab[2*action + 1];
      sSym[idx] = (short)ch1; sAct[idx] = (short)action;
      int j1 = idx + 1; if (j1 > STK-1) j1 = STK-1;
      sSym[j1] = (short)ch0; sAct[j1] = (short)action;
      int np = idx + 2; if (np > STK) np = STK;
      sPtr = np; sPrev = action;
      if (b == 0) out[t] = (float)action;
    }
    __syncthreads();
    ++eix;
  }

  if (b == 0){
    for (int i = tid; i < HID_; i += NTHR){
      out[NSTEP + i]        = gload(h1g + i);
      out[NSTEP + HID_ + i] = gload(h2g + i);
    }
  }
}

extern "C" void kernel_launch(void* const* d_in, const int* in_sizes, int n_in,
                              void* d_out, int out_size, void* d_ws, size_t ws_size,
                              hipStream_t stream) {
  (void)in_sizes; (void)n_in; (void)out_size; (void)ws_size;
  const float* emb  = (const float*)d_in[0];
  const float* Wih1 = (const float*)d_in[1];
  const float* Whh1 = (const float*)d_in[2];
  const float* bih1 = (const float*)d_in[3];
  const float* bhh1 = (const float*)d_in[4];
  const float* Wih2 = (const float*)d_in[5];
  const float* Whh2 = (const float*)d_in[6];
  const float* bih2 = (const float*)d_in[7];
  const float* bhh2 = (const float*)d_in[8];
  const float* Wa   = (const float*)d_in[9];
  const float* ba   = (const float*)d_in[10];
  const float* h0   = (const float*)d_in[11];
  const int*   ctab = (const int*)d_in[12];
  float* out = (float*)d_out;

  // ws layout (12288 B total, within round-5 proven envelope):
  // [0,1024)    per-XCD leaf counters (local scope), 8 x 128B
  // [1024,2048) per-XCD release flags (local scope), 8 x 128B
  // [2048,2080) arr8 epoch slots (agent)
  // [2176,2208) xcdCount[8] (agent) ; [2304] initCnt ; [2432] initFlag
  // [3072,3104) winner u64[4] rotating (agent)
  // [4096,8192) h1g ; [8192,12288) h2g
  char* ws = (char*)d_ws;
  unsigned* ctrl = (unsigned*)ws;
  unsigned long long* winner = (unsigned long long*)(ws + 3072);
  float* h1g = (float*)(ws + 4096);
  float* h2g = (float*)(ws + 8192);

  hipMemsetAsync(d_ws, 0, 4096, stream);   // zero all control state
  tree_gen<<<NBLK, NTHR, 0, stream>>>(emb, Wih1, Whh1, bih1, bhh1, Wih2, Whh2,
                                      bih2, bhh2, Wa, ba, h0, ctab, out,
                                      h1g, h2g, winner, ctrl);
}